// Round 1
// baseline (633.939 us; speedup 1.0000x reference)
//
#include <hip/hip_runtime.h>
#include <hip/hip_bf16.h>
#include <math.h>

#define NHEADS 8
#define CHVAL 32

// atomic max for float via int/uint ordering trick.
// Works for mixed signs given init bits 0xFF800000 (-inf).
__device__ __forceinline__ void atomicMaxFloat(float* addr, float val) {
    if (val >= 0.0f) {
        atomicMax((int*)addr, __float_as_int(val));
    } else {
        atomicMin((unsigned int*)addr, __float_as_uint(val));
    }
}

__global__ void init_kernel(float* __restrict__ m, float* __restrict__ s, int n) {
    int i = blockIdx.x * blockDim.x + threadIdx.x;
    if (i < n) {
        m[i] = -INFINITY;
        s[i] = 0.0f;
    }
}

// one thread per (edge, head): 16-feature dot product, atomic max into m
__global__ void logits_kernel(const float4* __restrict__ key0,   // [E*8] float4
                              const float4* __restrict__ key1,   // [E*24] float4
                              const float4* __restrict__ q0,     // [N*8] float4
                              const float4* __restrict__ q1,     // [N*24] float4
                              const int* __restrict__ dst,
                              float* __restrict__ logits,        // [E*8]
                              float* __restrict__ m,             // [N*8]
                              int EH) {
    int tid = blockIdx.x * blockDim.x + threadIdx.x;
    if (tid >= EH) return;
    int e = tid >> 3;
    int h = tid & 7;
    int n = dst[e];
    int qh = n * 8 + h;

    float4 a = key0[tid];
    float4 qa = q0[qh];
    float dot = a.x * qa.x + a.y * qa.y + a.z * qa.z + a.w * qa.w;
#pragma unroll
    for (int j = 0; j < 3; ++j) {
        float4 b  = key1[tid * 3 + j];
        float4 qb = q1[qh * 3 + j];
        dot += b.x * qb.x + b.y * qb.y + b.z * qb.z + b.w * qb.w;
    }
    float lg = dot * 0.08838834764831845f;  // 1/sqrt(128)
    logits[tid] = lg;
    atomicMaxFloat(&m[qh], lg);
}

// ex = exp(logit - m[dst]); atomic sum into s; overwrite logits with ex
__global__ void exp_kernel(const int* __restrict__ dst,
                           float* __restrict__ logits,  // in: logit, out: ex
                           const float* __restrict__ m,
                           float* __restrict__ s,
                           int EH) {
    int tid = blockIdx.x * blockDim.x + threadIdx.x;
    if (tid >= EH) return;
    int e = tid >> 3;
    int h = tid & 7;
    int nh = dst[e] * 8 + h;
    float ex = expf(logits[tid] - m[nh]);
    logits[tid] = ex;
    atomicAdd(&s[nh], ex);
}

// one thread per (edge, channel): w = ex/s, scatter-add weighted values
__global__ void agg_kernel(const float* __restrict__ value0,  // [E*32]
                           const float* __restrict__ value1,  // [E*96]
                           const int* __restrict__ dst,
                           const float* __restrict__ ex,      // [E*8]
                           const float* __restrict__ s,       // [N*8]
                           float* __restrict__ out0,          // [N*32]
                           float* __restrict__ out1,          // [N*96]
                           int EC) {
    int tid = blockIdx.x * blockDim.x + threadIdx.x;
    if (tid >= EC) return;
    int e = tid >> 5;
    int c = tid & 31;
    int h = c >> 2;
    int n = dst[e];
    float w = ex[e * 8 + h] / s[n * 8 + h];

    atomicAdd(&out0[n * 32 + c], w * value0[tid]);

    int vb = e * 96 + c * 3;
    int ob = n * 96 + c * 3;
    atomicAdd(&out1[ob + 0], w * value1[vb + 0]);
    atomicAdd(&out1[ob + 1], w * value1[vb + 1]);
    atomicAdd(&out1[ob + 2], w * value1[vb + 2]);
}

extern "C" void kernel_launch(void* const* d_in, const int* in_sizes, int n_in,
                              void* d_out, int out_size, void* d_ws, size_t ws_size,
                              hipStream_t stream) {
    const float* key0   = (const float*)d_in[0];
    const float* key1   = (const float*)d_in[1];
    const float* value0 = (const float*)d_in[2];
    const float* value1 = (const float*)d_in[3];
    const float* query0 = (const float*)d_in[4];
    const float* query1 = (const float*)d_in[5];
    const int*   dst    = (const int*)d_in[6];

    int E = in_sizes[0] / CHVAL;   // key0 is E*32*1
    int N = in_sizes[4] / CHVAL;   // query0 is N*32*1
    int EH = E * NHEADS;
    int NH = N * NHEADS;
    int EC = E * CHVAL;

    float* wsf    = (float*)d_ws;
    float* logits = wsf;            // EH floats (becomes ex)
    float* m      = wsf + EH;       // NH floats
    float* s      = wsf + EH + NH;  // NH floats

    float* out0 = (float*)d_out;        // N*32
    float* out1 = out0 + (size_t)N * 32; // N*96

    hipMemsetAsync(d_out, 0, (size_t)out_size * sizeof(float), stream);

    int blk = 256;
    init_kernel<<<(NH + blk - 1) / blk, blk, 0, stream>>>(m, s, NH);

    logits_kernel<<<(EH + blk - 1) / blk, blk, 0, stream>>>(
        (const float4*)key0, (const float4*)key1,
        (const float4*)query0, (const float4*)query1,
        dst, logits, m, EH);

    exp_kernel<<<(EH + blk - 1) / blk, blk, 0, stream>>>(dst, logits, m, s, EH);

    agg_kernel<<<(EC + blk - 1) / blk, blk, 0, stream>>>(
        value0, value1, dst, logits, s, out0, out1, EC);
}

// Round 4
// 320.964 us; speedup vs baseline: 1.9751x; 1.9751x over previous
//
#include <hip/hip_runtime.h>
#include <hip/hip_bf16.h>
#include <math.h>

#define NHEADS 8
#define CHVAL 32
#define SCAN_BLOCK 1024

// Per (edge,head): 16-feature dot product -> logits. Head 0 also histograms dst.
__global__ void logits_kernel(const float4* __restrict__ key0,   // [E*8] float4
                              const float4* __restrict__ key1,   // [E*24] float4
                              const float4* __restrict__ q0,     // [N*8] float4
                              const float4* __restrict__ q1,     // [N*24] float4
                              const int* __restrict__ dst,
                              float* __restrict__ logits,        // [E*8]
                              int* __restrict__ cnt,             // [N]
                              int EH) {
    int tid = blockIdx.x * blockDim.x + threadIdx.x;
    if (tid >= EH) return;
    int e = tid >> 3;
    int h = tid & 7;
    int n = dst[e];
    int qh = n * 8 + h;

    float4 a = key0[tid];
    float4 qa = q0[qh];
    float dot = a.x * qa.x + a.y * qa.y + a.z * qa.z + a.w * qa.w;
#pragma unroll
    for (int j = 0; j < 3; ++j) {
        float4 b  = key1[tid * 3 + j];
        float4 qb = q1[qh * 3 + j];
        dot += b.x * qb.x + b.y * qb.y + b.z * qb.z + b.w * qb.w;
    }
    logits[tid] = dot * 0.08838834764831845f;  // 1/sqrt(128)
    if (h == 0) atomicAdd(&cnt[n], 1);
}

// Single-workgroup exclusive scan of cnt[0..N) -> offs[0..N]; also init cursor.
__global__ void scan_kernel(const int* __restrict__ cnt,
                            int* __restrict__ offs,
                            int* __restrict__ cursor,
                            int N) {
    __shared__ int sh[SCAN_BLOCK];
    int t = threadIdx.x;
    int running = 0;
    for (int base = 0; base < N; base += SCAN_BLOCK) {
        int i = base + t;
        int v = (i < N) ? cnt[i] : 0;
        sh[t] = v;
        __syncthreads();
        for (int off = 1; off < SCAN_BLOCK; off <<= 1) {
            int y = (t >= off) ? sh[t - off] : 0;
            __syncthreads();
            sh[t] += y;
            __syncthreads();
        }
        int excl = sh[t] - v;
        if (i < N) {
            offs[i] = running + excl;
            cursor[i] = running + excl;
        }
        int chunk_total = sh[SCAN_BLOCK - 1];
        __syncthreads();
        running += chunk_total;
    }
    if (t == 0) offs[N] = running;
}

// Bucket edges by dst into eid[] using cursor.
__global__ void scatter_kernel(const int* __restrict__ dst,
                               int* __restrict__ cursor,
                               int* __restrict__ eid,
                               int E) {
    int e = blockIdx.x * blockDim.x + threadIdx.x;
    if (e < E) {
        int pos = atomicAdd(&cursor[dst[e]], 1);
        eid[pos] = e;
    }
}

// One workgroup (128 threads) per node: softmax over incoming edges + weighted
// value aggregation, all in LDS/registers. No atomics. Each thread owns one
// output channel.
__global__ void __launch_bounds__(128)
node_kernel(const float* __restrict__ logits,   // [E*8]
            const float* __restrict__ value0,   // [E*32]
            const float* __restrict__ value1,   // [E*96]
            const int* __restrict__ offs,       // [N+1]
            const int* __restrict__ eid,        // [E]
            float* __restrict__ out0,           // [N*32]
            float* __restrict__ out1) {         // [N*96]
    int n = blockIdx.x;
    int t = threadIdx.x;              // 0..127
    int beg = offs[n];
    int deg = offs[n + 1] - beg;

    __shared__ float red[16][8];
    __shared__ float m_sh[8];
    __shared__ float inv_s_sh[8];

    int h = t & 7;
    int sub = t >> 3;                 // 16 subgroups of 8

    // phase 1a: per-head max
    float mx = -INFINITY;
    for (int i = sub; i < deg; i += 16)
        mx = fmaxf(mx, logits[(size_t)eid[beg + i] * 8 + h]);
    red[sub][h] = mx;
    __syncthreads();
    if (t < 8) {
        float m = red[0][t];
#pragma unroll
        for (int j = 1; j < 16; ++j) m = fmaxf(m, red[j][t]);
        m_sh[t] = m;
    }
    __syncthreads();

    // phase 1b: per-head sum of exp
    float mh = m_sh[h];
    float sm = 0.0f;
    for (int i = sub; i < deg; i += 16)
        sm += expf(logits[(size_t)eid[beg + i] * 8 + h] - mh);
    red[sub][h] = sm;
    __syncthreads();
    if (t < 8) {
        float s = red[0][t];
#pragma unroll
        for (int j = 1; j < 16; ++j) s += red[j][t];
        inv_s_sh[t] = 1.0f / s;
    }
    __syncthreads();

    // phase 2: accumulate one output channel per thread
    bool isV0 = t < 32;
    int f = t - 32;                        // value1 flat index (when !isV0)
    int myh = isV0 ? (t >> 2) : ((f / 3) >> 2);
    float mh2 = m_sh[myh];
    float is  = inv_s_sh[myh];

    float acc = 0.0f;
    for (int i = 0; i < deg; ++i) {
        int e = eid[beg + i];
        float w = expf(logits[(size_t)e * 8 + myh] - mh2) * is;
        float v = isV0 ? value0[(size_t)e * 32 + t]
                       : value1[(size_t)e * 96 + f];
        acc += w * v;
    }

    if (isV0) out0[(size_t)n * 32 + t] = acc;
    else      out1[(size_t)n * 96 + f] = acc;
}

extern "C" void kernel_launch(void* const* d_in, const int* in_sizes, int n_in,
                              void* d_out, int out_size, void* d_ws, size_t ws_size,
                              hipStream_t stream) {
    const float* key0   = (const float*)d_in[0];
    const float* key1   = (const float*)d_in[1];
    const float* value0 = (const float*)d_in[2];
    const float* value1 = (const float*)d_in[3];
    const float* query0 = (const float*)d_in[4];
    const float* query1 = (const float*)d_in[5];
    const int*   dst    = (const int*)d_in[6];

    int E = in_sizes[0] / CHVAL;   // 500000
    int N = in_sizes[4] / CHVAL;   // 50000
    int EH = E * NHEADS;

    // workspace layout (4-byte elements)
    float* logits = (float*)d_ws;            // EH floats
    int*   cnt    = (int*)(logits + EH);     // N
    int*   offs   = cnt + N;                 // N+1
    int*   cursor = offs + N + 1;            // N
    int*   eid    = cursor + N;              // E

    float* out0 = (float*)d_out;             // N*32
    float* out1 = out0 + (size_t)N * 32;     // N*96

    hipMemsetAsync(cnt, 0, (size_t)N * sizeof(int), stream);

    int blk = 256;
    logits_kernel<<<(EH + blk - 1) / blk, blk, 0, stream>>>(
        (const float4*)key0, (const float4*)key1,
        (const float4*)query0, (const float4*)query1,
        dst, logits, cnt, EH);

    scan_kernel<<<1, SCAN_BLOCK, 0, stream>>>(cnt, offs, cursor, N);

    scatter_kernel<<<(E + blk - 1) / blk, blk, 0, stream>>>(dst, cursor, eid, E);

    node_kernel<<<N, 128, 0, stream>>>(logits, value0, value1, offs, eid,
                                       out0, out1);
}

// Round 5
// 226.302 us; speedup vs baseline: 2.8013x; 1.4183x over previous
//
#include <hip/hip_runtime.h>
#include <hip/hip_bf16.h>
#include <math.h>

#define NHEADS 8
#define CHVAL 32
#define SCB 1024

// Per (edge,head): 16-feature dot product -> logits. Head 0 also histograms dst.
__global__ void logits_kernel(const float4* __restrict__ key0,   // [E*8] float4
                              const float4* __restrict__ key1,   // [E*24] float4
                              const float4* __restrict__ q0,     // [N*8] float4
                              const float4* __restrict__ q1,     // [N*24] float4
                              const int* __restrict__ dst,
                              float* __restrict__ logits,        // [E*8]
                              int* __restrict__ cnt,             // [N]
                              int EH) {
    int tid = blockIdx.x * blockDim.x + threadIdx.x;
    if (tid >= EH) return;
    int e = tid >> 3;
    int h = tid & 7;
    int n = dst[e];
    int qh = n * 8 + h;

    float4 a = key0[tid];
    float4 qa = q0[qh];
    float dot = a.x * qa.x + a.y * qa.y + a.z * qa.z + a.w * qa.w;
#pragma unroll
    for (int j = 0; j < 3; ++j) {
        float4 b  = key1[tid * 3 + j];
        float4 qb = q1[qh * 3 + j];
        dot += b.x * qb.x + b.y * qb.y + b.z * qb.z + b.w * qb.w;
    }
    logits[tid] = dot * 0.08838834764831845f;  // 1/sqrt(128)
    if (h == 0) atomicAdd(&cnt[n], 1);
}

// Pass 1: per-block exclusive scan of cnt (in place), block totals -> btot.
__global__ void scan1_kernel(int* __restrict__ cnt, int* __restrict__ btot, int N) {
    __shared__ int sh[SCB];
    int t = threadIdx.x;
    int i = blockIdx.x * SCB + t;
    int v = (i < N) ? cnt[i] : 0;
    sh[t] = v;
    __syncthreads();
    for (int off = 1; off < SCB; off <<= 1) {
        int y = (t >= off) ? sh[t - off] : 0;
        __syncthreads();
        sh[t] += y;
        __syncthreads();
    }
    if (i < N) cnt[i] = sh[t] - v;          // exclusive within block
    if (t == SCB - 1) btot[blockIdx.x] = sh[t];
}

// Pass 2: single small block scans the (<=64) block totals, exclusive, in place.
__global__ void scan2_kernel(int* __restrict__ btot, int nb) {
    __shared__ int sh[64];
    int t = threadIdx.x;
    int v = (t < nb) ? btot[t] : 0;
    sh[t] = v;
    __syncthreads();
    for (int off = 1; off < 64; off <<= 1) {
        int y = (t >= off) ? sh[t - off] : 0;
        __syncthreads();
        sh[t] += y;
        __syncthreads();
    }
    if (t < nb) btot[t] = sh[t] - v;
}

// Pass 3: offs/cursor = local + block offset; offs[N] = E.
__global__ void scan3_kernel(const int* __restrict__ cnt, const int* __restrict__ btot,
                             int* __restrict__ offs, int* __restrict__ cursor,
                             int N, int E) {
    int i = blockIdx.x * blockDim.x + threadIdx.x;
    if (i < N) {
        int o = cnt[i] + btot[i >> 10];
        offs[i] = o;
        cursor[i] = o;
    }
    if (i == 0) offs[N] = E;
}

// Bucket edges by dst into eid[] using cursor.
__global__ void scatter_kernel(const int* __restrict__ dst,
                               int* __restrict__ cursor,
                               int* __restrict__ eid,
                               int E) {
    int e = blockIdx.x * blockDim.x + threadIdx.x;
    if (e < E) {
        int pos = atomicAdd(&cursor[dst[e]], 1);
        eid[pos] = e;
    }
}

// One workgroup (128 threads) per node. Softmax weights computed once per
// (edge,head) into LDS; values accumulated with float4 loads, 4 edges in
// flight (one per 32-lane group); 4-way LDS reduce at the end. No atomics.
__global__ void __launch_bounds__(128)
node_kernel(const float* __restrict__ logits,    // [E*8]
            const float4* __restrict__ value0,   // [E*8]  float4
            const float4* __restrict__ value1,   // [E*24] float4
            const int* __restrict__ offs,        // [N+1]
            const int* __restrict__ eid,         // [E]
            float4* __restrict__ out0,           // [N*8]  float4
            float4* __restrict__ out1) {         // [N*24] float4
    int n = blockIdx.x;
    int t = threadIdx.x;              // 0..127
    int beg = offs[n];
    int deg = offs[n + 1] - beg;

    __shared__ float red[16][8];
    __shared__ float m_sh[8];
    __shared__ float inv_s_sh[8];
    __shared__ float w_sh[64][8];
    __shared__ int   e_sh[64];
    __shared__ float4 racc[128];

    int h = t & 7;
    int sub = t >> 3;                 // 16 subgroups of 8

    // phase 1a: per-head max
    float mx = -INFINITY;
    for (int i = sub; i < deg; i += 16)
        mx = fmaxf(mx, logits[(size_t)eid[beg + i] * 8 + h]);
    red[sub][h] = mx;
    __syncthreads();
    if (t < 8) {
        float m = red[0][t];
#pragma unroll
        for (int j = 1; j < 16; ++j) m = fmaxf(m, red[j][t]);
        m_sh[t] = m;
    }
    __syncthreads();

    // phase 1b: per-head sum of exp
    float mh = m_sh[h];
    float sm = 0.0f;
    for (int i = sub; i < deg; i += 16)
        sm += expf(logits[(size_t)eid[beg + i] * 8 + h] - mh);
    red[sub][h] = sm;
    __syncthreads();
    if (t < 8) {
        float s = red[0][t];
#pragma unroll
        for (int j = 1; j < 16; ++j) s += red[j][t];
        inv_s_sh[t] = 1.0f / s;
    }
    __syncthreads();

    // phase 2: chunked weight precompute + float4 accumulation
    int g = t >> 5;                   // 4 edge-groups
    int l = t & 31;                   // lane owns 4 output floats
    int myh = (l < 8) ? l : (l - 8) / 3;   // each value float4 is single-head
    float4 acc = {0.f, 0.f, 0.f, 0.f};

    for (int cbase = 0; cbase < deg; cbase += 64) {
        int clen = min(64, deg - cbase);
        for (int p = t; p < clen; p += 128)
            e_sh[p] = eid[beg + cbase + p];
        for (int p = t; p < clen * 8; p += 128) {
            int i = p >> 3, hh = p & 7;
            int e = eid[beg + cbase + i];
            w_sh[i][hh] = expf(logits[(size_t)e * 8 + hh] - m_sh[hh]) * inv_s_sh[hh];
        }
        __syncthreads();
        for (int ii = g; ii < clen; ii += 4) {
            int e = e_sh[ii];
            float w = w_sh[ii][myh];
            float4 v = (l < 8) ? value0[(size_t)e * 8 + l]
                               : value1[(size_t)e * 24 + (l - 8)];
            acc.x += w * v.x;
            acc.y += w * v.y;
            acc.z += w * v.z;
            acc.w += w * v.w;
        }
        __syncthreads();
    }

    racc[t] = acc;
    __syncthreads();
    if (t < 32) {
        float4 a = racc[t], b = racc[t + 32], c = racc[t + 64], d = racc[t + 96];
        float4 r;
        r.x = a.x + b.x + c.x + d.x;
        r.y = a.y + b.y + c.y + d.y;
        r.z = a.z + b.z + c.z + d.z;
        r.w = a.w + b.w + c.w + d.w;
        if (t < 8) out0[(size_t)n * 8 + t] = r;
        else       out1[(size_t)n * 24 + (t - 8)] = r;
    }
}

extern "C" void kernel_launch(void* const* d_in, const int* in_sizes, int n_in,
                              void* d_out, int out_size, void* d_ws, size_t ws_size,
                              hipStream_t stream) {
    const float* key0   = (const float*)d_in[0];
    const float* key1   = (const float*)d_in[1];
    const float* value0 = (const float*)d_in[2];
    const float* value1 = (const float*)d_in[3];
    const float* query0 = (const float*)d_in[4];
    const float* query1 = (const float*)d_in[5];
    const int*   dst    = (const int*)d_in[6];

    int E = in_sizes[0] / CHVAL;   // 500000
    int N = in_sizes[4] / CHVAL;   // 50000
    int EH = E * NHEADS;
    int nb = (N + SCB - 1) / SCB;  // 49

    // workspace layout (4-byte elements)
    float* logits = (float*)d_ws;            // EH
    int*   cnt    = (int*)(logits + EH);     // N (reused as local-scan)
    int*   offs   = cnt + N;                 // N+1
    int*   cursor = offs + N + 1;            // N
    int*   eid    = cursor + N;              // E
    int*   btot   = eid + E;                 // 64

    float* out0 = (float*)d_out;             // N*32
    float* out1 = out0 + (size_t)N * 32;     // N*96

    hipMemsetAsync(cnt, 0, (size_t)N * sizeof(int), stream);

    int blk = 256;
    logits_kernel<<<(EH + blk - 1) / blk, blk, 0, stream>>>(
        (const float4*)key0, (const float4*)key1,
        (const float4*)query0, (const float4*)query1,
        dst, logits, cnt, EH);

    scan1_kernel<<<nb, SCB, 0, stream>>>(cnt, btot, N);
    scan2_kernel<<<1, 64, 0, stream>>>(btot, nb);
    scan3_kernel<<<(N + blk - 1) / blk, blk, 0, stream>>>(cnt, btot, offs, cursor, N, E);

    scatter_kernel<<<(E + blk - 1) / blk, blk, 0, stream>>>(dst, cursor, eid, E);

    node_kernel<<<N, 128, 0, stream>>>(logits,
                                       (const float4*)value0, (const float4*)value1,
                                       offs, eid,
                                       (float4*)out0, (float4*)out1);
}

// Round 6
// 189.896 us; speedup vs baseline: 3.3384x; 1.1917x over previous
//
#include <hip/hip_runtime.h>
#include <hip/hip_bf16.h>
#include <math.h>

#define NHEADS 8
#define CHVAL 32
#define SCB 1024
#define WPB 4   // waves (nodes) per block in node_kernel

// Per (edge,head): 16-feature dot product -> logits. Head 0 also histograms dst.
__global__ void logits_kernel(const float4* __restrict__ key0,   // [E*8] float4
                              const float4* __restrict__ key1,   // [E*24] float4
                              const float4* __restrict__ q0,     // [N*8] float4
                              const float4* __restrict__ q1,     // [N*24] float4
                              const int* __restrict__ dst,
                              float* __restrict__ logits,        // [E*8]
                              int* __restrict__ cnt,             // [N]
                              int EH) {
    int tid = blockIdx.x * blockDim.x + threadIdx.x;
    if (tid >= EH) return;
    int e = tid >> 3;
    int h = tid & 7;
    int n = dst[e];
    int qh = n * 8 + h;

    float4 a = key0[tid];
    float4 qa = q0[qh];
    float dot = a.x * qa.x + a.y * qa.y + a.z * qa.z + a.w * qa.w;
#pragma unroll
    for (int j = 0; j < 3; ++j) {
        float4 b  = key1[tid * 3 + j];
        float4 qb = q1[qh * 3 + j];
        dot += b.x * qb.x + b.y * qb.y + b.z * qb.z + b.w * qb.w;
    }
    logits[tid] = dot * 0.08838834764831845f;  // 1/sqrt(128)
    if (h == 0) atomicAdd(&cnt[n], 1);
}

// Pass 1: per-block exclusive scan of cnt (in place), block totals -> btot.
__global__ void scan1_kernel(int* __restrict__ cnt, int* __restrict__ btot, int N) {
    __shared__ int sh[SCB];
    int t = threadIdx.x;
    int i = blockIdx.x * SCB + t;
    int v = (i < N) ? cnt[i] : 0;
    sh[t] = v;
    __syncthreads();
    for (int off = 1; off < SCB; off <<= 1) {
        int y = (t >= off) ? sh[t - off] : 0;
        __syncthreads();
        sh[t] += y;
        __syncthreads();
    }
    if (i < N) cnt[i] = sh[t] - v;          // exclusive within block
    if (t == SCB - 1) btot[blockIdx.x] = sh[t];
}

// Pass 2: single small block scans the (<=64) block totals, exclusive, in place.
__global__ void scan2_kernel(int* __restrict__ btot, int nb) {
    __shared__ int sh[64];
    int t = threadIdx.x;
    int v = (t < nb) ? btot[t] : 0;
    sh[t] = v;
    __syncthreads();
    for (int off = 1; off < 64; off <<= 1) {
        int y = (t >= off) ? sh[t - off] : 0;
        __syncthreads();
        sh[t] += y;
        __syncthreads();
    }
    if (t < nb) btot[t] = sh[t] - v;
}

// Pass 3: offs/cursor = local + block offset; offs[N] = E.
__global__ void scan3_kernel(const int* __restrict__ cnt, const int* __restrict__ btot,
                             int* __restrict__ offs, int* __restrict__ cursor,
                             int N, int E) {
    int i = blockIdx.x * blockDim.x + threadIdx.x;
    if (i < N) {
        int o = cnt[i] + btot[i >> 10];
        offs[i] = o;
        cursor[i] = o;
    }
    if (i == 0) offs[N] = E;
}

// Bucket edges by dst into eid[] using cursor.
__global__ void scatter_kernel(const int* __restrict__ dst,
                               int* __restrict__ cursor,
                               int* __restrict__ eid,
                               int E) {
    int e = blockIdx.x * blockDim.x + threadIdx.x;
    if (e < E) {
        int pos = atomicAdd(&cursor[dst[e]], 1);
        eid[pos] = e;
    }
}

// One WAVE (64 lanes) per node; WPB waves per block, fully independent
// (disjoint LDS slices, no s_barrier). Lane i owns edge slot i: loads the
// edge's 8 logits as 2x float4, per-head max/sum via register shuffles,
// weights parked in LDS, values accumulated with float4 loads (2 edges in
// flight per wave), cross-half shuffle reduce, coalesced store.
__global__ void __launch_bounds__(64 * WPB)
node_kernel(const float* __restrict__ logits,    // [E*8]
            const float4* __restrict__ value0,   // [E*8]  float4
            const float4* __restrict__ value1,   // [E*24] float4
            const int* __restrict__ offs,        // [N+1]
            const int* __restrict__ eid,         // [E]
            float4* __restrict__ out0,           // [N*8]  float4
            float4* __restrict__ out1,           // [N*24] float4
            int N) {
    __shared__ float w_sh[WPB][64][9];           // padded: stride 9 banks

    int wv = threadIdx.x >> 6;
    int t  = threadIdx.x & 63;
    int n  = blockIdx.x * WPB + wv;
    if (n >= N) return;

    int beg = offs[n];
    int deg = offs[n + 1] - beg;

    if (deg == 0) {
        float4 z = {0.f, 0.f, 0.f, 0.f};
        if (t < 8) out0[(size_t)n * 8 + t] = z;
        else if (t < 32) out1[(size_t)n * 24 + (t - 8)] = z;
        return;
    }

    // gather chunk-0 logits: lane i -> edge slot i, 8 heads (32B contiguous)
    int myeid = -1;
    float lg[8];
    if (t < deg) {
        myeid = eid[beg + t];
        const float4* lp = (const float4*)(logits + (size_t)myeid * 8);
        float4 a = lp[0], b = lp[1];
        lg[0] = a.x; lg[1] = a.y; lg[2] = a.z; lg[3] = a.w;
        lg[4] = b.x; lg[5] = b.y; lg[6] = b.z; lg[7] = b.w;
    } else {
#pragma unroll
        for (int k = 0; k < 8; ++k) lg[k] = -INFINITY;
    }

    // per-head max (running over rare extra chunks)
    float mx[8];
#pragma unroll
    for (int k = 0; k < 8; ++k) mx[k] = lg[k];
    for (int base = 64; base < deg; base += 64) {       // rare: deg > 64
        if (base + t < deg) {
            int e = eid[beg + base + t];
            const float4* lp = (const float4*)(logits + (size_t)e * 8);
            float4 a = lp[0], b = lp[1];
            float tt[8] = {a.x, a.y, a.z, a.w, b.x, b.y, b.z, b.w};
#pragma unroll
            for (int k = 0; k < 8; ++k) mx[k] = fmaxf(mx[k], tt[k]);
        }
    }
#pragma unroll
    for (int k = 0; k < 8; ++k)
        for (int off = 32; off; off >>= 1)
            mx[k] = fmaxf(mx[k], __shfl_xor(mx[k], off, 64));

    // per-head sum of exp (exp(-inf - m) = 0 handles inactive lanes)
    float ex0[8], sm[8];
#pragma unroll
    for (int k = 0; k < 8; ++k) { ex0[k] = __expf(lg[k] - mx[k]); sm[k] = ex0[k]; }
    for (int base = 64; base < deg; base += 64) {       // rare
        if (base + t < deg) {
            int e = eid[beg + base + t];
            const float4* lp = (const float4*)(logits + (size_t)e * 8);
            float4 a = lp[0], b = lp[1];
            float tt[8] = {a.x, a.y, a.z, a.w, b.x, b.y, b.z, b.w};
#pragma unroll
            for (int k = 0; k < 8; ++k) sm[k] += __expf(tt[k] - mx[k]);
        }
    }
#pragma unroll
    for (int k = 0; k < 8; ++k)
        for (int off = 32; off; off >>= 1)
            sm[k] += __shfl_xor(sm[k], off, 64);
    float inv[8];
#pragma unroll
    for (int k = 0; k < 8; ++k) inv[k] = 1.0f / sm[k];

    // value accumulation: each 32-lane half owns alternate edges; lane's
    // float4 is a single-head slice (myh) of value0/value1.
    int half = t >> 5;
    int l = t & 31;
    int myh = (l < 8) ? l : ((l - 8) / 3);
    float4 acc = {0.f, 0.f, 0.f, 0.f};

    for (int base = 0; base < deg; base += 64) {
        int clen = min(64, deg - base);
        if (base == 0) {
            if (t < clen) {
#pragma unroll
                for (int k = 0; k < 8; ++k) w_sh[wv][t][k] = ex0[k] * inv[k];
            }
        } else {                                        // rare
            if (base + t < deg) {
                int e = eid[beg + base + t];
                const float4* lp = (const float4*)(logits + (size_t)e * 8);
                float4 a = lp[0], b = lp[1];
                float tt[8] = {a.x, a.y, a.z, a.w, b.x, b.y, b.z, b.w};
#pragma unroll
                for (int k = 0; k < 8; ++k)
                    w_sh[wv][t][k] = __expf(tt[k] - mx[k]) * inv[k];
            }
        }
        __builtin_amdgcn_wave_barrier();  // compiler fence: DS pipe is in-order per wave

        for (int ii = half; ii < clen; ii += 2) {
            int e = (base == 0) ? __shfl(myeid, ii, 64)
                                : eid[beg + base + ii];
            float w = w_sh[wv][ii][myh];
            float4 v = (l < 8) ? value0[(size_t)e * 8 + l]
                               : value1[(size_t)e * 24 + (l - 8)];
            acc.x += w * v.x;
            acc.y += w * v.y;
            acc.z += w * v.z;
            acc.w += w * v.w;
        }
        __builtin_amdgcn_wave_barrier();
    }

    // cross-half reduce, lanes 0-31 store
    acc.x += __shfl_xor(acc.x, 32, 64);
    acc.y += __shfl_xor(acc.y, 32, 64);
    acc.z += __shfl_xor(acc.z, 32, 64);
    acc.w += __shfl_xor(acc.w, 32, 64);
    if (t < 8)       out0[(size_t)n * 8 + l] = acc;
    else if (t < 32) out1[(size_t)n * 24 + (l - 8)] = acc;
}

extern "C" void kernel_launch(void* const* d_in, const int* in_sizes, int n_in,
                              void* d_out, int out_size, void* d_ws, size_t ws_size,
                              hipStream_t stream) {
    const float* key0   = (const float*)d_in[0];
    const float* key1   = (const float*)d_in[1];
    const float* value0 = (const float*)d_in[2];
    const float* value1 = (const float*)d_in[3];
    const float* query0 = (const float*)d_in[4];
    const float* query1 = (const float*)d_in[5];
    const int*   dst    = (const int*)d_in[6];

    int E = in_sizes[0] / CHVAL;   // 500000
    int N = in_sizes[4] / CHVAL;   // 50000
    int EH = E * NHEADS;
    int nb = (N + SCB - 1) / SCB;  // 49

    // workspace layout (4-byte elements)
    float* logits = (float*)d_ws;            // EH
    int*   cnt    = (int*)(logits + EH);     // N (reused as local-scan)
    int*   offs   = cnt + N;                 // N+1
    int*   cursor = offs + N + 1;            // N
    int*   eid    = cursor + N;              // E
    int*   btot   = eid + E;                 // 64

    float* out0 = (float*)d_out;             // N*32
    float* out1 = out0 + (size_t)N * 32;     // N*96

    hipMemsetAsync(cnt, 0, (size_t)N * sizeof(int), stream);

    int blk = 256;
    logits_kernel<<<(EH + blk - 1) / blk, blk, 0, stream>>>(
        (const float4*)key0, (const float4*)key1,
        (const float4*)query0, (const float4*)query1,
        dst, logits, cnt, EH);

    scan1_kernel<<<nb, SCB, 0, stream>>>(cnt, btot, N);
    scan2_kernel<<<1, 64, 0, stream>>>(btot, nb);
    scan3_kernel<<<(N + blk - 1) / blk, blk, 0, stream>>>(cnt, btot, offs, cursor, N, E);

    scatter_kernel<<<(E + blk - 1) / blk, blk, 0, stream>>>(dst, cursor, eid, E);

    int nnb = (N + WPB - 1) / WPB;
    node_kernel<<<nnb, 64 * WPB, 0, stream>>>(logits,
                                              (const float4*)value0,
                                              (const float4*)value1,
                                              offs, eid,
                                              (float4*)out0, (float4*)out1, N);
}